// Round 5
// baseline (1022.166 us; speedup 1.0000x reference)
//
#include <hip/hip_runtime.h>
#include <hip/hip_cooperative_groups.h>
#include <hip/hip_bf16.h>
#include <math.h>

namespace cg = cooperative_groups;

typedef __attribute__((ext_vector_type(8))) short bf16x8;
typedef __attribute__((ext_vector_type(4))) float f32x4;

constexpr int Bn = 64;    // batch (dialogues)
constexpr int Ln = 512;   // utterances
constexpr int Hd = 768;   // hidden
constexpr int Nn = 50;    // nodes per dialogue
constexpr int On = 768;   // output dim

// ===========================================================================
// Tile-level helpers, shared by the cooperative mega-kernel and the
// multi-launch fallback. Each assumes all 256 threads participate and is
// free of LDS hazards across repeated calls (ends in __syncthreads or only
// touches LDS before its internal barriers).

__device__ __forceinline__ void transpose_tile(const float* W,
                                               __hip_bfloat16* Wt, int t,
                                               char* smem) {
  float(*tile)[33] = (float(*)[33])smem;
  int bx = (t % 24) * 32, by = (t / 24) * 32;
  int c = threadIdx.x & 31, r0 = threadIdx.x >> 5;
  for (int r = r0; r < 32; r += 8)
    tile[r][c] = W[(size_t)(bx + r) * Hd + by + c];
  __syncthreads();
  for (int r = r0; r < 32; r += 8)
    Wt[(size_t)(by + r) * Hd + bx + c] = __float2bfloat16(tile[c][r]);
  __syncthreads();
}

__device__ __forceinline__ void gather_pe_row(const float* emb, const int* ids,
                                              float* xf, __hip_bfloat16* xb,
                                              int bn) {
  int b = bn / Nn, n = bn % Nn;
  int id = ids[bn];
  const float* src = emb + ((size_t)b * Ln + id) * Hd;
  float* xo = xf + (size_t)bn * Hd;
  __hip_bfloat16* xbo = xb + (size_t)bn * Hd;
  const float kLog = 9.210340371976184f / (float)Hd;  // ln(10000)/H
  for (int h = threadIdx.x; h < Hd; h += 256) {
    int he = h & ~1;
    float freq = expf(-(float)he * kLog);
    float ang = (float)n * freq;
    float pe = (h & 1) ? cosf(ang) : sinf(ang);
    float v = src[h] + pe;
    xo[h] = v;
    xbo[h] = __float2bfloat16(v);
  }
}

// C[64,64] tile of A[M,768] @ Bt[768,768]^T + bias.
// EPI 0: write C (f32) + fused src/dst dots into o1/o2 (atomic).
// EPI 1: no C write; t = tanh(C+bias); atomicAdd(o1[row], t . avec).
template <int EPI>
__device__ __forceinline__ void gemm_tile(
    const __hip_bfloat16* A, const __hip_bfloat16* Bt, const float* bias,
    float* C, const float* avec, float* o1, float* o2, int row0, int col0,
    char* smem) {
  __hip_bfloat16(*As)[40] = (__hip_bfloat16(*)[40])smem;
  __hip_bfloat16(*Bs)[40] = (__hip_bfloat16(*)[40])(smem + 5120);
  int tid = threadIdx.x;
  int wave = tid >> 6, lane = tid & 63;
  int lr = lane & 15, lq = lane >> 4;
  int sr = tid >> 2, sk = (tid & 3) * 8;
  const __hip_bfloat16* Ap = A + (size_t)(row0 + sr) * Hd + sk;
  const __hip_bfloat16* Bp = Bt + (size_t)(col0 + sr) * Hd + sk;
  f32x4 acc[4] = {};
  for (int kt = 0; kt < Hd; kt += 32) {
    *(uint4*)&As[sr][sk] = *(const uint4*)(Ap + kt);
    *(uint4*)&Bs[sr][sk] = *(const uint4*)(Bp + kt);
    __syncthreads();
    bf16x8 af = *(const bf16x8*)&As[wave * 16 + lr][lq * 8];
#pragma unroll
    for (int ct = 0; ct < 4; ++ct) {
      bf16x8 bfrag = *(const bf16x8*)&Bs[ct * 16 + lr][lq * 8];
      acc[ct] = __builtin_amdgcn_mfma_f32_16x16x32_bf16(af, bfrag, acc[ct], 0, 0, 0);
    }
    __syncthreads();
  }
  int cr0 = row0 + wave * 16 + lq * 4;
  if (EPI == 0) {
    float ps[4] = {}, pd[4] = {};
#pragma unroll
    for (int ct = 0; ct < 4; ++ct) {
      int gc = col0 + ct * 16 + lr;
      float bv = bias[gc];
      float as_ = avec[gc], ad_ = avec[Hd + gc];
#pragma unroll
      for (int r = 0; r < 4; ++r) {
        float v = acc[ct][r] + bv;
        C[(size_t)(cr0 + r) * Hd + gc] = v;
        ps[r] += v * as_;
        pd[r] += v * ad_;
      }
    }
#pragma unroll
    for (int off = 8; off; off >>= 1)
#pragma unroll
      for (int r = 0; r < 4; ++r) {
        ps[r] += __shfl_xor(ps[r], off);
        pd[r] += __shfl_xor(pd[r], off);
      }
    if (lr == 0)
#pragma unroll
      for (int r = 0; r < 4; ++r) {
        atomicAdd(&o1[cr0 + r], ps[r]);
        atomicAdd(&o2[cr0 + r], pd[r]);
      }
  } else {
    float pr[4] = {};
#pragma unroll
    for (int ct = 0; ct < 4; ++ct) {
      int gc = col0 + ct * 16 + lr;
      float bv = bias[gc];
      float vv_ = avec[gc];
#pragma unroll
      for (int r = 0; r < 4; ++r) {
        float t = tanhf(acc[ct][r] + bv);
        pr[r] += t * vv_;
      }
    }
#pragma unroll
    for (int off = 8; off; off >>= 1)
#pragma unroll
      for (int r = 0; r < 4; ++r) pr[r] += __shfl_xor(pr[r], off);
    if (lr == 0)
#pragma unroll
      for (int r = 0; r < 4; ++r) atomicAdd(&o1[cr0 + r], pr[r]);
  }
}

// Fused GAT attention for one (dialogue b, 128-wide h-chunk).
template <int LAYER>
__device__ __forceinline__ void attf_tile(
    const float* ssrc, const float* sdst, const int* adj, const float* ab,
    const float* Wh, const float* xres, float* hf, __hip_bfloat16* hb, int b,
    int h0, char* smem) {
  float* attL = (float*)smem;
  float abv = ab[0];
  for (int idx = threadIdx.x; idx < Nn * Nn; idx += 256) {
    int i = idx / Nn, j = idx - i * Nn;
    float t = ssrc[b * Nn + i] + sdst[b * Nn + j] + abv;
    t = t > 0.f ? t : 0.3f * t;  // leaky_relu alpha=0.3
    attL[idx] = (adj[(size_t)b * Nn * Nn + idx] > 0) ? t : -9.0e15f;
  }
  __syncthreads();
  if (threadIdx.x < Nn) {
    int i = threadIdx.x;
    float m = -3.0e38f;
    for (int j = 0; j < Nn; ++j) m = fmaxf(m, attL[i * Nn + j]);
    float s = 0.f;
    for (int j = 0; j < Nn; ++j) {
      float p = expf(attL[i * Nn + j] - m);
      attL[i * Nn + j] = p;
      s += p;
    }
    float inv = 1.f / s;
    for (int j = 0; j < Nn; ++j) attL[i * Nn + j] *= inv;
  }
  __syncthreads();
  int col = threadIdx.x & 127, half = threadIdx.x >> 7;
  int i0 = half * 25;
  float acc[25] = {};
  const float* Whb = Wh + ((size_t)b * Nn) * Hd + h0 + col;
  for (int j = 0; j < Nn; j += 2) {
    float w0 = Whb[(size_t)j * Hd];
    float w1 = Whb[(size_t)(j + 1) * Hd];
#pragma unroll
    for (int ii = 0; ii < 25; ++ii) {
      float2 a2 = *(const float2*)&attL[(i0 + ii) * Nn + j];
      acc[ii] += a2.x * w0 + a2.y * w1;
    }
  }
#pragma unroll
  for (int ii = 0; ii < 25; ++ii) {
    float v = acc[ii];
    v = v > 0.f ? v : expf(v) - 1.f;  // elu
    size_t off = ((size_t)b * Nn + i0 + ii) * Hd + h0 + col;
    if (LAYER == 2) {
      v += xres[off];
      hf[off] = v;
    }
    hb[off] = __float2bfloat16(v);
  }
  __syncthreads();
}

__device__ __forceinline__ void poolfinal_tile(
    const float* sraw, const float* h2, const __hip_bfloat16* Wlt,
    const float* bl, float* out, int b, char* smem) {
  float* sc = (float*)smem;
  float* ds = (float*)(smem + 256);
  if (threadIdx.x < 64) {
    int j = threadIdx.x;
    float e = (j < Nn) ? sraw[b * Nn + j] : -3.0e38f;
    float m = e;
#pragma unroll
    for (int off = 32; off; off >>= 1) m = fmaxf(m, __shfl_xor(m, off));
    float p = (j < Nn) ? expf(e - m) : 0.f;
    float s = p;
#pragma unroll
    for (int off = 32; off; off >>= 1) s += __shfl_xor(s, off);
    if (j < Nn) sc[j] = p / s;
  }
  __syncthreads();
  for (int h = threadIdx.x; h < Hd; h += 256) {
    float a = 0.f;
#pragma unroll 10
    for (int j = 0; j < Nn; ++j) a += sc[j] * h2[((size_t)b * Nn + j) * Hd + h];
    ds[h] = a;
  }
  __syncthreads();
  for (int oo = 0; oo < 3; ++oo) {
    int o = oo * 256 + threadIdx.x;
    float acc = bl[o];
    const uint4* wr = (const uint4*)(Wlt + (size_t)o * Hd);
    for (int kk = 0; kk < Hd / 8; ++kk) {
      union { uint4 u; unsigned short s[8]; } w;
      w.u = wr[kk];
#pragma unroll
      for (int t = 0; t < 8; ++t)
        acc += ds[kk * 8 + t] * __uint_as_float((unsigned)w.s[t] << 16);
    }
    out[(size_t)b * On + o] = acc;
  }
  __syncthreads();
}

// ===========================================================================
struct MegaArgs {
  const float* emb; const int* ids; const int* adj;
  const float* W1; const float* b1; const float* a1; const float* ab1;
  const float* W2; const float* b2; const float* a2; const float* ab2;
  const float* Wa; const float* ba; const float* vv;
  const float* Wl; const float* bl;
  float* out;
  __hip_bfloat16 *Wt1, *Wt2, *Wta, *Wlt;
  float* aux;  // ssrc1,sdst1,ssrc2,sdst2,sraw (5*Bn*Nn)
  float *xf, *Wh, *h2f;
  __hip_bfloat16 *xb, *hb;
};

__global__ __launch_bounds__(256, 2) void mega_kernel(MegaArgs a) {
  cg::grid_group grid = cg::this_grid();
  __shared__ alignas(16) char smem[10496];
  const int G = gridDim.x;

  // ---- phase 0: weight cvt+transpose, gather+PE, zero accumulators ----
  {
    const float* src[4] = {a.W1, a.W2, a.Wa, a.Wl};
    __hip_bfloat16* dst[4] = {a.Wt1, a.Wt2, a.Wta, a.Wlt};
    for (int t = blockIdx.x; t < 4 * 576; t += G)
      transpose_tile(src[t / 576], dst[t / 576], t % 576, smem);
    for (int bn = blockIdx.x; bn < Bn * Nn; bn += G)
      gather_pe_row(a.emb, a.ids, a.xf, a.xb, bn);
    for (int i = blockIdx.x * 256 + threadIdx.x; i < 5 * Bn * Nn; i += G * 256)
      a.aux[i] = 0.f;
  }
  float* ssrc1 = a.aux;
  float* sdst1 = a.aux + Bn * Nn;
  float* ssrc2 = a.aux + 2 * Bn * Nn;
  float* sdst2 = a.aux + 3 * Bn * Nn;
  float* sraw = a.aux + 4 * Bn * Nn;
  __threadfence();
  grid.sync();

  for (int t = blockIdx.x; t < 600; t += G)
    gemm_tile<0>(a.xb, a.Wt1, a.b1, a.Wh, a.a1, ssrc1, sdst1, (t % 50) * 64,
                 (t / 50) * 64, smem);
  __threadfence();
  grid.sync();

  for (int t = blockIdx.x; t < 6 * Bn; t += G)
    attf_tile<1>(ssrc1, sdst1, a.adj, a.ab1, a.Wh, nullptr, nullptr, a.hb,
                 t / 6, (t % 6) * 128, smem);
  __threadfence();
  grid.sync();

  for (int t = blockIdx.x; t < 600; t += G)
    gemm_tile<0>(a.hb, a.Wt2, a.b2, a.Wh, a.a2, ssrc2, sdst2, (t % 50) * 64,
                 (t / 50) * 64, smem);
  __threadfence();
  grid.sync();

  for (int t = blockIdx.x; t < 6 * Bn; t += G)
    attf_tile<2>(ssrc2, sdst2, a.adj, a.ab2, a.Wh, a.xf, a.h2f, a.hb, t / 6,
                 (t % 6) * 128, smem);
  __threadfence();
  grid.sync();

  for (int t = blockIdx.x; t < 600; t += G)
    gemm_tile<1>(a.hb, a.Wta, a.ba, nullptr, a.vv, sraw, nullptr, (t % 50) * 64,
                 (t / 50) * 64, smem);
  __threadfence();
  grid.sync();

  for (int b = blockIdx.x; b < Bn; b += G)
    poolfinal_tile(sraw, a.h2f, a.Wlt, a.bl, a.out, b, smem);
}

// ===========================================================================
// Fallback multi-launch kernels (Round-3 pipeline, proven correct).

struct PrepArgs {
  const float* src[4];
  __hip_bfloat16* dst[4];
  float* aux;
  int auxn;
};

__global__ __launch_bounds__(256) void prep_kernel(PrepArgs args) {
  __shared__ alignas(16) char smem[4352];
  int job = blockIdx.y;
  if (job < 4) {
    transpose_tile(args.src[job], args.dst[job], blockIdx.x, smem);
  } else {
    int idx = blockIdx.x * 256 + threadIdx.x;
    if (idx < args.auxn) args.aux[idx] = 0.f;
  }
}

__global__ __launch_bounds__(256) void gather_pe_kernel(
    const float* __restrict__ emb, const int* __restrict__ ids,
    float* __restrict__ xf, __hip_bfloat16* __restrict__ xb) {
  gather_pe_row(emb, ids, xf, xb, blockIdx.x);
}

template <int EPI>
__global__ __launch_bounds__(256) void gemm_kernel(
    const __hip_bfloat16* __restrict__ A, const __hip_bfloat16* __restrict__ Bt,
    const float* __restrict__ bias, float* __restrict__ C,
    const float* __restrict__ avec, float* __restrict__ o1,
    float* __restrict__ o2) {
  __shared__ alignas(16) char smem[10240];
  gemm_tile<EPI>(A, Bt, bias, C, avec, o1, o2, blockIdx.x * 64,
                 blockIdx.y * 64, smem);
}

template <int LAYER>
__global__ __launch_bounds__(256) void attf_kernel(
    const float* __restrict__ ssrc, const float* __restrict__ sdst,
    const int* __restrict__ adj, const float* __restrict__ ab,
    const float* __restrict__ Wh, const float* __restrict__ xres,
    float* __restrict__ hf, __hip_bfloat16* __restrict__ hb) {
  __shared__ alignas(16) char smem[10016];
  attf_tile<LAYER>(ssrc, sdst, adj, ab, Wh, xres, hf, hb, blockIdx.x / 6,
                   (blockIdx.x % 6) * 128, smem);
}

__global__ __launch_bounds__(256) void poolfinal_kernel(
    const float* __restrict__ sraw, const float* __restrict__ h2,
    const __hip_bfloat16* __restrict__ Wlt, const float* __restrict__ bl,
    float* __restrict__ out) {
  __shared__ alignas(16) char smem[3584];
  poolfinal_tile(sraw, h2, Wlt, bl, out, blockIdx.x, smem);
}

// ===========================================================================
extern "C" void kernel_launch(void* const* d_in, const int* in_sizes, int n_in,
                              void* d_out, int out_size, void* d_ws, size_t ws_size,
                              hipStream_t stream) {
  char* p = (char*)d_ws;
  auto alloc = [&](size_t bytes) {
    char* r = p;
    p += (bytes + 255) & ~(size_t)255;
    return r;
  };
  MegaArgs a;
  a.emb = (const float*)d_in[0];
  a.ids = (const int*)d_in[1];
  a.adj = (const int*)d_in[2];
  a.W1 = (const float*)d_in[3];  a.b1 = (const float*)d_in[4];
  a.a1 = (const float*)d_in[5];  a.ab1 = (const float*)d_in[6];
  a.W2 = (const float*)d_in[7];  a.b2 = (const float*)d_in[8];
  a.a2 = (const float*)d_in[9];  a.ab2 = (const float*)d_in[10];
  a.Wa = (const float*)d_in[11]; a.ba = (const float*)d_in[12];
  a.vv = (const float*)d_in[13];
  a.Wl = (const float*)d_in[14]; a.bl = (const float*)d_in[15];
  a.out = (float*)d_out;

  a.Wt1 = (__hip_bfloat16*)alloc((size_t)Hd * Hd * 2);
  a.Wt2 = (__hip_bfloat16*)alloc((size_t)Hd * Hd * 2);
  a.Wta = (__hip_bfloat16*)alloc((size_t)Hd * Hd * 2);
  a.Wlt = (__hip_bfloat16*)alloc((size_t)Hd * On * 2);
  a.aux = (float*)alloc(5 * Bn * Nn * 4);
  a.xf = (float*)alloc((size_t)Bn * Nn * Hd * 4);
  a.xb = (__hip_bfloat16*)alloc((size_t)Bn * Nn * Hd * 2);
  a.Wh = (float*)alloc((size_t)Bn * Nn * Hd * 4);
  a.h2f = (float*)alloc((size_t)Bn * Nn * Hd * 4);
  a.hb = (__hip_bfloat16*)alloc((size_t)Bn * Nn * Hd * 2);

  // ---- pre-flight: can we cooperatively launch, and at what grid? ----
  bool coop_ok = false;
  int grid = 0;
  {
    int dev = 0;
    (void)hipGetDevice(&dev);
    int attr = 0;
    if (hipDeviceGetAttribute(&attr, hipDeviceAttributeCooperativeLaunch,
                              dev) == hipSuccess && attr) {
      int numCU = 0, maxB = 0;
      if (hipDeviceGetAttribute(&numCU,
                                hipDeviceAttributeMultiprocessorCount,
                                dev) == hipSuccess &&
          hipOccupancyMaxActiveBlocksPerMultiprocessor(&maxB, mega_kernel, 256,
                                                       0) == hipSuccess) {
        grid = maxB * numCU;
        if (grid > 600) grid = 600;
        if (grid >= 64) coop_ok = true;
      }
    }
  }

  if (coop_ok) {
    void* params[] = {(void*)&a};
    hipError_t err = hipLaunchCooperativeKernel(
        mega_kernel, dim3(grid), dim3(256), params, 0, stream);
    if (err != hipSuccess) {
      (void)hipGetLastError();  // clear sticky error, take fallback
      coop_ok = false;
    }
  }

  if (!coop_ok) {
    float* ssrc1 = a.aux;
    float* sdst1 = a.aux + Bn * Nn;
    float* ssrc2 = a.aux + 2 * Bn * Nn;
    float* sdst2 = a.aux + 3 * Bn * Nn;
    float* sraw = a.aux + 4 * Bn * Nn;

    PrepArgs pa;
    pa.src[0] = a.W1; pa.src[1] = a.W2; pa.src[2] = a.Wa; pa.src[3] = a.Wl;
    pa.dst[0] = a.Wt1; pa.dst[1] = a.Wt2; pa.dst[2] = a.Wta; pa.dst[3] = a.Wlt;
    pa.aux = a.aux; pa.auxn = 5 * Bn * Nn;
    prep_kernel<<<dim3(576, 5), 256, 0, stream>>>(pa);

    gather_pe_kernel<<<Bn * Nn, 256, 0, stream>>>(a.emb, a.ids, a.xf, a.xb);

    dim3 ggrid(Bn * Nn / 64, Hd / 64);  // 50 x 12
    dim3 agrid(6 * Bn);                 // 384

    gemm_kernel<0><<<ggrid, 256, 0, stream>>>(a.xb, a.Wt1, a.b1, a.Wh, a.a1,
                                              ssrc1, sdst1);
    attf_kernel<1><<<agrid, 256, 0, stream>>>(ssrc1, sdst1, a.adj, a.ab1, a.Wh,
                                              nullptr, nullptr, a.hb);
    gemm_kernel<0><<<ggrid, 256, 0, stream>>>(a.hb, a.Wt2, a.b2, a.Wh, a.a2,
                                              ssrc2, sdst2);
    attf_kernel<2><<<agrid, 256, 0, stream>>>(ssrc2, sdst2, a.adj, a.ab2, a.Wh,
                                              a.xf, a.h2f, a.hb);
    gemm_kernel<1><<<ggrid, 256, 0, stream>>>(a.hb, a.Wta, a.ba, nullptr, a.vv,
                                              sraw, nullptr);
    poolfinal_kernel<<<Bn, 256, 0, stream>>>(sraw, a.h2f, a.Wlt, a.bl, a.out);
  }
}

// Round 6
// 305.848 us; speedup vs baseline: 3.3421x; 3.3421x over previous
//
#include <hip/hip_runtime.h>
#include <hip/hip_bf16.h>
#include <math.h>

typedef __attribute__((ext_vector_type(8))) short bf16x8;
typedef __attribute__((ext_vector_type(4))) float f32x4;

constexpr int Bn = 64;    // batch (dialogues)
constexpr int Ln = 512;   // utterances
constexpr int Hd = 768;   // hidden
constexpr int Nn = 50;    // nodes per dialogue
constexpr int On = 768;   // output dim

// ===========================================================================
// prep: one kernel, three job ranges by blockIdx.x:
//   [0, 2304)        : 32x32 transpose+cvt tiles of W1,W2,Wa,Wl (f32 -> bf16^T)
//   [2304, 5504)     : gather CLS rows + sinusoidal PE -> xf (f32) + xb (bf16)
//   [5504, 5567)     : zero the 5*Bn*Nn atomic accumulator region
struct PrepArgs {
  const float* src[4];
  __hip_bfloat16* dst[4];
  const float* emb;
  const int* ids;
  float* xf;
  __hip_bfloat16* xb;
  float* aux;
  int auxn;
};

__global__ __launch_bounds__(256) void prep_kernel(PrepArgs a) {
  __shared__ float tile[32][33];
  int bx = blockIdx.x;
  if (bx < 2304) {
    int job = bx / 576, t = bx % 576;
    const float* W = a.src[job];
    __hip_bfloat16* Wt = a.dst[job];
    int tx = (t % 24) * 32, ty = (t / 24) * 32;
    int c = threadIdx.x & 31, r0 = threadIdx.x >> 5;
    for (int r = r0; r < 32; r += 8)
      tile[r][c] = W[(size_t)(tx + r) * Hd + ty + c];
    __syncthreads();
    for (int r = r0; r < 32; r += 8)
      Wt[(size_t)(ty + r) * Hd + tx + c] = __float2bfloat16(tile[c][r]);
  } else if (bx < 5504) {
    int bn = bx - 2304;  // b*Nn + n
    int b = bn / Nn, n = bn % Nn;
    int id = a.ids[bn];
    const float* src = a.emb + ((size_t)b * Ln + id) * Hd;
    float* xo = a.xf + (size_t)bn * Hd;
    __hip_bfloat16* xbo = a.xb + (size_t)bn * Hd;
    const float kLog = 9.210340371976184f / (float)Hd;  // ln(10000)/H
    for (int h = threadIdx.x; h < Hd; h += 256) {
      int he = h & ~1;
      float freq = expf(-(float)he * kLog);
      float ang = (float)n * freq;
      float pe = (h & 1) ? cosf(ang) : sinf(ang);
      float v = src[h] + pe;
      xo[h] = v;
      xbo[h] = __float2bfloat16(v);
    }
  } else {
    int idx = (bx - 5504) * 256 + threadIdx.x;
    if (idx < a.auxn) a.aux[idx] = 0.f;
  }
}

// ===========================================================================
// C[M,768] = A[M,768] @ Bt[768,768]^T + bias. Double-buffered LDS, one
// barrier per K-step.
// EPI 0: write C as bf16 + fused src/dst dots (f32, from registers) into
//        o1/o2 via atomics.
// EPI 1: no C write; t = tanh(C+bias); atomicAdd(o1[row], t . avec).
template <int EPI>
__global__ __launch_bounds__(256) void gemm_kernel(
    const __hip_bfloat16* __restrict__ A, const __hip_bfloat16* __restrict__ Bt,
    const float* __restrict__ bias, __hip_bfloat16* __restrict__ C,
    const float* __restrict__ avec, float* __restrict__ o1,
    float* __restrict__ o2) {
  __shared__ __hip_bfloat16 As[2][64][40];  // pad 40: write 2-way (free),
  __shared__ __hip_bfloat16 Bs[2][64][40];  // read 2-way (free) per m136
  int tid = threadIdx.x;
  int wave = tid >> 6, lane = tid & 63;
  int lr = lane & 15, lq = lane >> 4;
  int row0 = blockIdx.x * 64, col0 = blockIdx.y * 64;
  int sr = tid >> 2, sk = (tid & 3) * 8;
  const __hip_bfloat16* Ap = A + (size_t)(row0 + sr) * Hd + sk;
  const __hip_bfloat16* Bp = Bt + (size_t)(col0 + sr) * Hd + sk;
  uint4 ra = *(const uint4*)Ap;
  uint4 rb = *(const uint4*)Bp;
  *(uint4*)&As[0][sr][sk] = ra;
  *(uint4*)&Bs[0][sr][sk] = rb;
  f32x4 acc[4] = {};
  __syncthreads();
  int cur = 0;
  for (int kt = 32; kt < Hd; kt += 32) {
    ra = *(const uint4*)(Ap + kt);  // prefetch next K-tile (global)
    rb = *(const uint4*)(Bp + kt);
    bf16x8 af = *(const bf16x8*)&As[cur][wave * 16 + lr][lq * 8];
#pragma unroll
    for (int ct = 0; ct < 4; ++ct) {
      bf16x8 bfrag = *(const bf16x8*)&Bs[cur][ct * 16 + lr][lq * 8];
      acc[ct] = __builtin_amdgcn_mfma_f32_16x16x32_bf16(af, bfrag, acc[ct], 0, 0, 0);
    }
    *(uint4*)&As[cur ^ 1][sr][sk] = ra;  // other buffer: no read hazard
    *(uint4*)&Bs[cur ^ 1][sr][sk] = rb;
    __syncthreads();
    cur ^= 1;
  }
  {
    bf16x8 af = *(const bf16x8*)&As[cur][wave * 16 + lr][lq * 8];
#pragma unroll
    for (int ct = 0; ct < 4; ++ct) {
      bf16x8 bfrag = *(const bf16x8*)&Bs[cur][ct * 16 + lr][lq * 8];
      acc[ct] = __builtin_amdgcn_mfma_f32_16x16x32_bf16(af, bfrag, acc[ct], 0, 0, 0);
    }
  }
  int cr0 = row0 + wave * 16 + lq * 4;
  if (EPI == 0) {
    float ps[4] = {}, pd[4] = {};
#pragma unroll
    for (int ct = 0; ct < 4; ++ct) {
      int gc = col0 + ct * 16 + lr;
      float bv = bias[gc];
      float as_ = avec[gc], ad_ = avec[Hd + gc];
#pragma unroll
      for (int r = 0; r < 4; ++r) {
        float v = acc[ct][r] + bv;
        C[(size_t)(cr0 + r) * Hd + gc] = __float2bfloat16(v);
        ps[r] += v * as_;
        pd[r] += v * ad_;
      }
    }
#pragma unroll
    for (int off = 8; off; off >>= 1)
#pragma unroll
      for (int r = 0; r < 4; ++r) {
        ps[r] += __shfl_xor(ps[r], off);
        pd[r] += __shfl_xor(pd[r], off);
      }
    if (lr == 0)
#pragma unroll
      for (int r = 0; r < 4; ++r) {
        atomicAdd(&o1[cr0 + r], ps[r]);
        atomicAdd(&o2[cr0 + r], pd[r]);
      }
  } else {
    float pr[4] = {};
#pragma unroll
    for (int ct = 0; ct < 4; ++ct) {
      int gc = col0 + ct * 16 + lr;
      float bv = bias[gc];
      float vv_ = avec[gc];
#pragma unroll
      for (int r = 0; r < 4; ++r) {
        float t = tanhf(acc[ct][r] + bv);
        pr[r] += t * vv_;
      }
    }
#pragma unroll
    for (int off = 8; off; off >>= 1)
#pragma unroll
      for (int r = 0; r < 4; ++r) pr[r] += __shfl_xor(pr[r], off);
    if (lr == 0)
#pragma unroll
      for (int r = 0; r < 4; ++r) atomicAdd(&o1[cr0 + r], pr[r]);
  }
}

// ===========================================================================
// Fused GAT attention: block = (dialogue b, 128-wide h-chunk).
// att = softmax(mask(adj, leaky_relu(ssrc_i + sdst_j + ab))) in LDS, then
// out[i, h0+col] = elu(sum_j att[i][j] * Wh[b][j][h0+col]) (+residual L2).
// Wh is bf16 (written by gemm EPI 0).
template <int LAYER>
__global__ __launch_bounds__(256) void attf_kernel(
    const float* __restrict__ ssrc, const float* __restrict__ sdst,
    const int* __restrict__ adj, const float* __restrict__ ab,
    const __hip_bfloat16* __restrict__ Wh, const float* __restrict__ xres,
    float* __restrict__ hf, __hip_bfloat16* __restrict__ hb) {
  int b = blockIdx.x / 6, h0 = (blockIdx.x % 6) * 128;
  __shared__ float attL[Nn * Nn];
  float abv = ab[0];
  for (int idx = threadIdx.x; idx < Nn * Nn; idx += 256) {
    int i = idx / Nn, j = idx - i * Nn;
    float t = ssrc[b * Nn + i] + sdst[b * Nn + j] + abv;
    t = t > 0.f ? t : 0.3f * t;  // leaky_relu alpha=0.3
    attL[idx] = (adj[(size_t)b * Nn * Nn + idx] > 0) ? t : -9.0e15f;
  }
  __syncthreads();
  if (threadIdx.x < Nn) {
    int i = threadIdx.x;
    float m = -3.0e38f;
    for (int j = 0; j < Nn; ++j) m = fmaxf(m, attL[i * Nn + j]);
    float s = 0.f;
    for (int j = 0; j < Nn; ++j) {
      float p = expf(attL[i * Nn + j] - m);
      attL[i * Nn + j] = p;
      s += p;
    }
    float inv = 1.f / s;
    for (int j = 0; j < Nn; ++j) attL[i * Nn + j] *= inv;
  }
  __syncthreads();
  int col = threadIdx.x & 127, half = threadIdx.x >> 7;
  int i0 = half * 25;
  float acc[25] = {};
  const __hip_bfloat16* Whb = Wh + ((size_t)b * Nn) * Hd + h0 + col;
  for (int j = 0; j < Nn; j += 2) {
    float w0 = __bfloat162float(Whb[(size_t)j * Hd]);
    float w1 = __bfloat162float(Whb[(size_t)(j + 1) * Hd]);
#pragma unroll
    for (int ii = 0; ii < 25; ++ii) {
      float2 a2 = *(const float2*)&attL[(i0 + ii) * Nn + j];
      acc[ii] += a2.x * w0 + a2.y * w1;
    }
  }
#pragma unroll
  for (int ii = 0; ii < 25; ++ii) {
    float v = acc[ii];
    v = v > 0.f ? v : expf(v) - 1.f;  // elu
    size_t off = ((size_t)b * Nn + i0 + ii) * Hd + h0 + col;
    if (LAYER == 2) {
      v += xres[off];
      hf[off] = v;
    }
    hb[off] = __float2bfloat16(v);
  }
}

// ===========================================================================
// Fused pooling + final linear. Block per dialogue b.
__global__ __launch_bounds__(256) void poolfinal_kernel(
    const float* __restrict__ sraw, const float* __restrict__ h2,
    const __hip_bfloat16* __restrict__ Wlt, const float* __restrict__ bl,
    float* __restrict__ out) {
  int b = blockIdx.x;
  __shared__ float sc[Nn];
  __shared__ float ds[Hd];
  if (threadIdx.x < 64) {
    int j = threadIdx.x;
    float e = (j < Nn) ? sraw[b * Nn + j] : -3.0e38f;
    float m = e;
#pragma unroll
    for (int off = 32; off; off >>= 1) m = fmaxf(m, __shfl_xor(m, off));
    float p = (j < Nn) ? expf(e - m) : 0.f;
    float s = p;
#pragma unroll
    for (int off = 32; off; off >>= 1) s += __shfl_xor(s, off);
    if (j < Nn) sc[j] = p / s;
  }
  __syncthreads();
  for (int h = threadIdx.x; h < Hd; h += 256) {
    float a = 0.f;
#pragma unroll 10
    for (int j = 0; j < Nn; ++j) a += sc[j] * h2[((size_t)b * Nn + j) * Hd + h];
    ds[h] = a;
  }
  __syncthreads();
  for (int oo = 0; oo < 3; ++oo) {
    int o = oo * 256 + threadIdx.x;
    float acc = bl[o];
    const uint4* wr = (const uint4*)(Wlt + (size_t)o * Hd);
    for (int kk = 0; kk < Hd / 8; ++kk) {
      union { uint4 u; unsigned short s[8]; } w;
      w.u = wr[kk];
#pragma unroll
      for (int t = 0; t < 8; ++t)
        acc += ds[kk * 8 + t] * __uint_as_float((unsigned)w.s[t] << 16);
    }
    out[(size_t)b * On + o] = acc;
  }
}

// ===========================================================================
extern "C" void kernel_launch(void* const* d_in, const int* in_sizes, int n_in,
                              void* d_out, int out_size, void* d_ws, size_t ws_size,
                              hipStream_t stream) {
  const float* emb = (const float*)d_in[0];
  const int* ids = (const int*)d_in[1];
  const int* adj = (const int*)d_in[2];
  const float* W1 = (const float*)d_in[3];
  const float* b1 = (const float*)d_in[4];
  const float* a1 = (const float*)d_in[5];
  const float* ab1 = (const float*)d_in[6];
  const float* W2 = (const float*)d_in[7];
  const float* b2 = (const float*)d_in[8];
  const float* a2 = (const float*)d_in[9];
  const float* ab2 = (const float*)d_in[10];
  const float* Wa = (const float*)d_in[11];
  const float* ba = (const float*)d_in[12];
  const float* vv = (const float*)d_in[13];
  const float* Wl = (const float*)d_in[14];
  const float* bl = (const float*)d_in[15];
  float* out = (float*)d_out;

  char* p = (char*)d_ws;
  auto alloc = [&](size_t bytes) {
    char* r = p;
    p += (bytes + 255) & ~(size_t)255;
    return r;
  };
  __hip_bfloat16* Wt1 = (__hip_bfloat16*)alloc((size_t)Hd * Hd * 2);
  __hip_bfloat16* Wt2 = (__hip_bfloat16*)alloc((size_t)Hd * Hd * 2);
  __hip_bfloat16* Wta = (__hip_bfloat16*)alloc((size_t)Hd * Hd * 2);
  __hip_bfloat16* Wlt = (__hip_bfloat16*)alloc((size_t)Hd * On * 2);
  float* aux = (float*)alloc(5 * Bn * Nn * 4);
  float* ssrc1 = aux;
  float* sdst1 = aux + Bn * Nn;
  float* ssrc2 = aux + 2 * Bn * Nn;
  float* sdst2 = aux + 3 * Bn * Nn;
  float* sraw = aux + 4 * Bn * Nn;
  float* xf = (float*)alloc((size_t)Bn * Nn * Hd * 4);
  __hip_bfloat16* xb = (__hip_bfloat16*)alloc((size_t)Bn * Nn * Hd * 2);
  __hip_bfloat16* Whb16 = (__hip_bfloat16*)alloc((size_t)Bn * Nn * Hd * 2);
  float* h2f = (float*)alloc((size_t)Bn * Nn * Hd * 4);
  __hip_bfloat16* hb = (__hip_bfloat16*)alloc((size_t)Bn * Nn * Hd * 2);

  PrepArgs pa;
  pa.src[0] = W1; pa.src[1] = W2; pa.src[2] = Wa; pa.src[3] = Wl;
  pa.dst[0] = Wt1; pa.dst[1] = Wt2; pa.dst[2] = Wta; pa.dst[3] = Wlt;
  pa.emb = emb; pa.ids = ids; pa.xf = xf; pa.xb = xb;
  pa.aux = aux; pa.auxn = 5 * Bn * Nn;
  prep_kernel<<<5567, 256, 0, stream>>>(pa);

  dim3 ggrid(Bn * Nn / 64, Hd / 64);  // 50 x 12
  dim3 agrid(6 * Bn);                 // 384

  // --- GAT layer 1 ---
  gemm_kernel<0><<<ggrid, 256, 0, stream>>>(xb, Wt1, b1, Whb16, a1, ssrc1,
                                            sdst1);
  attf_kernel<1><<<agrid, 256, 0, stream>>>(ssrc1, sdst1, adj, ab1, Whb16,
                                            nullptr, nullptr, hb);
  // --- GAT layer 2 (+ residual) ---
  gemm_kernel<0><<<ggrid, 256, 0, stream>>>(hb, Wt2, b2, Whb16, a2, ssrc2,
                                            sdst2);
  attf_kernel<2><<<agrid, 256, 0, stream>>>(ssrc2, sdst2, adj, ab2, Whb16, xf,
                                            h2f, hb);
  // --- pooling scores: sraw[row] = tanh(h2@Wa+ba) . v ---
  gemm_kernel<1><<<ggrid, 256, 0, stream>>>(hb, Wta, ba, nullptr, vv, sraw,
                                            nullptr);
  // --- pool + final linear ---
  poolfinal_kernel<<<Bn, 256, 0, stream>>>(sraw, h2f, Wlt, bl, out);
}